// Round 6
// baseline (725.754 us; speedup 1.0000x reference)
//
#include <hip/hip_runtime.h>
#include <hip/hip_fp16.h>

#define F_IN 256
#define HID 128

typedef _Float16 half8 __attribute__((ext_vector_type(8)));
typedef _Float16 half4v __attribute__((ext_vector_type(4)));
typedef float f32x4 __attribute__((ext_vector_type(4)));

// ---------------- graph preprocessing ----------------

__global__ void k_count2(const int* __restrict__ col_s, int E, int* __restrict__ cnt_s,
                         const int* __restrict__ col_k, int EK, int* __restrict__ cnt_k) {
  int e = blockIdx.x * blockDim.x + threadIdx.x;
  if (e < E) {
    atomicAdd(&cnt_s[col_s[e]], 1);
  } else {
    int f = e - E;
    if (f < EK) atomicAdd(&cnt_k[col_k[f]], 1);
  }
}

__global__ void k_scan_block(const int* __restrict__ in, int n, int* __restrict__ out,
                             int* __restrict__ bsum) {
  __shared__ int s[1024];
  int tid = threadIdx.x;
  int i = blockIdx.x * 1024 + tid;
  int v = (i < n) ? in[i] : 0;
  s[tid] = v;
  __syncthreads();
  for (int off = 1; off < 1024; off <<= 1) {
    int t = (tid >= off) ? s[tid - off] : 0;
    __syncthreads();
    s[tid] += t;
    __syncthreads();
  }
  if (i < n) out[i] = s[tid] - v;          // exclusive
  if (tid == 1023) bsum[blockIdx.x] = s[1023];
}

__global__ void k_scan_single(int* __restrict__ bsum, int nb, int* __restrict__ tail) {
  if (threadIdx.x == 0 && blockIdx.x == 0) {
    int run = 0;
    for (int b = 0; b < nb; ++b) { int t = bsum[b]; bsum[b] = run; run += t; }
    *tail = run;
  }
}

__global__ void k_add_off(int* __restrict__ out, const int* __restrict__ bsum, int n) {
  int i = blockIdx.x * blockDim.x + threadIdx.x;
  if (i < n) out[i] += bsum[i >> 10];
}

__global__ void k_scatter2(const int* __restrict__ row_s, const int* __restrict__ col_s, int E,
                           const int* __restrict__ offs_s, int* __restrict__ cur_s,
                           int* __restrict__ csr_s,
                           const int* __restrict__ row_k, const int* __restrict__ col_k, int EK,
                           const int* __restrict__ offs_k, int* __restrict__ cur_k,
                           int* __restrict__ csr_k) {
  int e = blockIdx.x * blockDim.x + threadIdx.x;
  if (e < E) {
    int c = col_s[e];
    int p = offs_s[c] + atomicAdd(&cur_s[c], 1);
    csr_s[p] = row_s[e];
  } else {
    int f = e - E;
    if (f < EK) {
      int c = col_k[f];
      int p = offs_k[c] + atomicAdd(&cur_k[c], 1);
      csr_k[p] = row_k[f];
    }
  }
}

// ---------------- W fp32 -> fp16 (all three, concatenated) ----------------

__global__ void k_cvt_w(const float* __restrict__ W0, const float* __restrict__ W1,
                        const float* __restrict__ W2, _Float16* __restrict__ Wh) {
  const int sz = HID * F_IN;                    // 32768
  int idx = (blockIdx.x * 256 + threadIdx.x) * 4;  // [0, 3*sz)
  const float* src = (idx < sz) ? (W0 + idx)
                   : (idx < 2 * sz) ? (W1 + idx - sz)
                   : (W2 + idx - 2 * sz);
  float4 v = *(const float4*)src;
  half4v o;
  o[0] = (_Float16)v.x; o[1] = (_Float16)v.y; o[2] = (_Float16)v.z; o[3] = (_Float16)v.w;
  *(half4v*)(Wh + idx) = o;
}

// ---------------- fused MFMA GEMM, LDS-tiled, write-coalesced ----------------
// Block = 32 nodes, 256 thr (4 waves). x tile (32x256) staged fp32->fp16 into
// LDS once, XOR-swizzled. Wave (mh,ch) owns 16 nodes x 64 contiguous cols
// (=128B/row -> full-line writes from one wave, round-4 evidence). Grid 1563
// -> 6.1 waves/SIMD for W-load latency hiding. acc=16 VGPR, target <=64 total.

__global__ __launch_bounds__(256, 8) void k_gemm3(
    const float* __restrict__ x, const _Float16* __restrict__ Wh,
    const float* __restrict__ b0, const float* __restrict__ b1, const float* __restrict__ b2,
    int n, const int* __restrict__ cnt_s, const int* __restrict__ cnt_k,
    _Float16* __restrict__ gS1, _Float16* __restrict__ gS2,
    _Float16* __restrict__ gF2s, _Float16* __restrict__ gF2k)
{
  __shared__ _Float16 xs[32 * F_IN];       // 16 KB, swizzled
  int tid = threadIdx.x;
  int m0 = blockIdx.x * 32;

  // ---- stage x tile: thread t -> row t>>3, cols [(t&7)*32, +32) ----
  {
    int r = tid >> 3;
    int cbase = (tid & 7) * 32;
    int gr = m0 + r; if (gr >= n) gr = n - 1;
    const float* src = x + (size_t)gr * F_IN + cbase;
    unsigned sw = (unsigned)((r & 7) << 4);
    char* drow = (char*)xs + r * (F_IN * 2);
#pragma unroll
    for (int i = 0; i < 4; ++i) {          // 4 x 16B blocks = 32 fp16
      float4 a = *(const float4*)(src + i * 8);
      float4 b = *(const float4*)(src + i * 8 + 4);
      half8 v;
      v[0] = (_Float16)a.x; v[1] = (_Float16)a.y; v[2] = (_Float16)a.z; v[3] = (_Float16)a.w;
      v[4] = (_Float16)b.x; v[5] = (_Float16)b.y; v[6] = (_Float16)b.z; v[7] = (_Float16)b.w;
      *(half8*)(drow + (((unsigned)(cbase * 2 + i * 16)) ^ sw)) = v;
    }
  }
  __syncthreads();

  int lane = tid & 63;
  int wv = tid >> 6;
  int mh = wv >> 1, ch = wv & 1;            // m-half (16 nodes), col-half (64 cols)
  int l15 = lane & 15, lhi = lane >> 4;
  int rloc = mh * 16 + l15;
  unsigned swr = (unsigned)((rloc & 7) << 4);
  const char* xrow = (const char*)xs + rloc * (F_IN * 2);

  int node = m0 + rloc;
  int cn = (node < n) ? node : (n - 1);
  float ss = rsqrtf((float)(cnt_s[cn] + 1));
  float sk = rsqrtf((float)(cnt_k[cn] + 1));

#pragma unroll 1
  for (int w = 0; w < 3; ++w) {
    const float* bias = (w == 0) ? b0 : (w == 1) ? b1 : b2;
    _Float16* dst = (w == 0) ? gS1 : (w == 1) ? gS2 : gF2s;
    const _Float16* Wp = Wh + (size_t)w * HID * F_IN
                            + (size_t)(ch * 64 + l15) * F_IN + lhi * 8;

    f32x4 acc[4];
#pragma unroll
    for (int nt = 0; nt < 4; ++nt) {
      float4 bv = *(const float4*)(bias + ch * 64 + nt * 16 + lhi * 4);
      acc[nt] = (f32x4){bv.x, bv.y, bv.z, bv.w};
    }

#pragma unroll
    for (int kt = 0; kt < 8; ++kt) {
      half8 xf = *(const half8*)(xrow + (((unsigned)((kt * 32 + lhi * 8) * 2)) ^ swr));
#pragma unroll
      for (int nt = 0; nt < 4; ++nt) {
        half8 wf = *(const half8*)(Wp + (size_t)nt * 16 * F_IN + kt * 32);
        acc[nt] = __builtin_amdgcn_mfma_f32_16x16x32_f16(wf, xf, acc[nt], 0, 0, 0);
      }
    }

    if (node < n) {
      size_t obase = (size_t)node * HID + ch * 64 + lhi * 4;
#pragma unroll
      for (int nt = 0; nt < 4; ++nt) {
        half4v o;
        o[0] = (_Float16)(acc[nt][0] * ss); o[1] = (_Float16)(acc[nt][1] * ss);
        o[2] = (_Float16)(acc[nt][2] * ss); o[3] = (_Float16)(acc[nt][3] * ss);
        *(half4v*)(dst + obase + nt * 16) = o;
      }
      if (w == 2) {
#pragma unroll
        for (int nt = 0; nt < 4; ++nt) {
          half4v o2;
          o2[0] = (_Float16)(acc[nt][0] * sk); o2[1] = (_Float16)(acc[nt][1] * sk);
          o2[2] = (_Float16)(acc[nt][2] * sk); o2[3] = (_Float16)(acc[nt][3] * sk);
          *(half4v*)(gF2k + obase + nt * 16) = o2;
        }
      }
    }
  }
}

// ---------------- SpMM (fp16 features) ----------------
// g'[i] = scale(i) * (g[i] + sum_src g[src]);  one wave per dest node, 1 dword/lane.
// mode 0: *1/deg -> fp16 out;  mode 1: *rsqrt(deg) -> fp32 out;  mode 2: mode1 + addsrc.

__device__ inline float2 h2f2(unsigned int u) {
  __half2 h; *(unsigned int*)&h = u; return __half22float2(h);
}

__device__ inline void spmm_store(void* out, size_t base, float2 acc, float deg, int mode,
                                  const float2* __restrict__ add) {
  if (mode == 0) {
    float sc = 1.0f / deg;
    __half2 h = __float22half2_rn(make_float2(acc.x * sc, acc.y * sc));
    ((__half2*)out)[base] = h;
  } else {
    float sc = rsqrtf(deg);
    float2 o = make_float2(acc.x * sc, acc.y * sc);
    if (mode == 2) { float2 z = add[base]; o.x += z.x; o.y += z.y; }
    ((float2*)out)[base] = o;
  }
}

__global__ __launch_bounds__(256) void k_spmm_h(
    const unsigned int* __restrict__ gin, void* __restrict__ gout,
    const int* __restrict__ csr, const int* __restrict__ offs, const int* __restrict__ cnt,
    int n, int mode, const float2* __restrict__ addsrc)
{
  int w = (blockIdx.x << 2) | ((int)threadIdx.x >> 6);
  if (w >= n) return;
  int lane = threadIdx.x & 63;
  int beg = offs[w], end = offs[w + 1];
  size_t base = (size_t)w * 64 + lane;
  float2 acc = h2f2(gin[base]);                  // self loop
  int e = beg;
#pragma unroll 1
  for (; e + 16 <= end; e += 16) {
    unsigned int u[16];
#pragma unroll
    for (int j = 0; j < 16; ++j)
      u[j] = gin[((size_t)(unsigned)csr[e + j] << 6) + lane];
    float sx = 0.f, sy = 0.f;
#pragma unroll
    for (int j = 0; j < 16; ++j) { float2 v = h2f2(u[j]); sx += v.x; sy += v.y; }
    acc.x += sx; acc.y += sy;
  }
#pragma unroll 1
  for (; e + 4 <= end; e += 4) {
    unsigned int u[4];
#pragma unroll
    for (int j = 0; j < 4; ++j)
      u[j] = gin[((size_t)(unsigned)csr[e + j] << 6) + lane];
    float sx = 0.f, sy = 0.f;
#pragma unroll
    for (int j = 0; j < 4; ++j) { float2 v = h2f2(u[j]); sx += v.x; sy += v.y; }
    acc.x += sx; acc.y += sy;
  }
  for (; e < end; ++e) {
    float2 v = h2f2(gin[((size_t)(unsigned)csr[e] << 6) + lane]);
    acc.x += v.x; acc.y += v.y;
  }
  spmm_store(gout, base, acc, (float)(cnt[w] + 1), mode, addsrc);
}

// 3 feature matrices propagated in one pass over the graph (shared steps 1,2)
__global__ __launch_bounds__(256) void k_spmm3(
    const unsigned int* __restrict__ g0, const unsigned int* __restrict__ g1,
    const unsigned int* __restrict__ g2,
    void* __restrict__ o0, void* __restrict__ o1, void* __restrict__ o2,
    int md0, int md1, int md2,
    const int* __restrict__ csr, const int* __restrict__ offs, const int* __restrict__ cnt,
    int n)
{
  int w = (blockIdx.x << 2) | ((int)threadIdx.x >> 6);
  if (w >= n) return;
  int lane = threadIdx.x & 63;
  int beg = offs[w], end = offs[w + 1];
  size_t base = (size_t)w * 64 + lane;
  float2 a0 = h2f2(g0[base]), a1 = h2f2(g1[base]), a2 = h2f2(g2[base]);
  int e = beg;
#pragma unroll 1
  for (; e + 4 <= end; e += 4) {
    size_t s[4];
#pragma unroll
    for (int j = 0; j < 4; ++j) s[j] = ((size_t)(unsigned)csr[e + j] << 6) + lane;
    unsigned int u0[4], u1[4], u2[4];
#pragma unroll
    for (int j = 0; j < 4; ++j) { u0[j] = g0[s[j]]; u1[j] = g1[s[j]]; u2[j] = g2[s[j]]; }
#pragma unroll
    for (int j = 0; j < 4; ++j) {
      float2 v;
      v = h2f2(u0[j]); a0.x += v.x; a0.y += v.y;
      v = h2f2(u1[j]); a1.x += v.x; a1.y += v.y;
      v = h2f2(u2[j]); a2.x += v.x; a2.y += v.y;
    }
  }
  for (; e < end; ++e) {
    size_t s0 = ((size_t)(unsigned)csr[e] << 6) + lane;
    float2 v;
    v = h2f2(g0[s0]); a0.x += v.x; a0.y += v.y;
    v = h2f2(g1[s0]); a1.x += v.x; a1.y += v.y;
    v = h2f2(g2[s0]); a2.x += v.x; a2.y += v.y;
  }
  float deg = (float)(cnt[w] + 1);
  spmm_store(o0, base, a0, deg, md0, nullptr);
  spmm_store(o1, base, a1, deg, md1, nullptr);
  spmm_store(o2, base, a2, deg, md2, nullptr);
}

// ---------------- launch ----------------

extern "C" void kernel_launch(void* const* d_in, const int* in_sizes, int n_in,
                              void* d_out, int out_size, void* d_ws, size_t ws_size,
                              hipStream_t stream) {
  const float* x    = (const float*)d_in[0];
  const int*   ei   = (const int*)d_in[1];
  const int*   knn  = (const int*)d_in[2];
  const float* W_s1 = (const float*)d_in[3];
  const float* b_s1 = (const float*)d_in[4];
  const float* W_s2 = (const float*)d_in[5];
  const float* b_s2 = (const float*)d_in[6];
  const float* W_f2 = (const float*)d_in[7];
  const float* b_f2 = (const float*)d_in[8];

  const int N  = in_sizes[0] / F_IN;
  const int E  = in_sizes[1] / 2;
  const int EK = in_sizes[2] / 2;
  const int* row_s = ei;   const int* col_s = ei + E;
  const int* row_k = knn;  const int* col_k = knn + EK;

  char* p = (char*)d_ws;
  auto carve = [&](size_t bytes) {
    char* r = p; p += (bytes + 511) & ~(size_t)511; return (void*)r;
  };
  int* cnt_s = (int*)carve((size_t)N * 4);
  int* cnt_k = (int*)carve((size_t)N * 4);
  int* cur_s = (int*)carve((size_t)N * 4);
  int* cur_k = (int*)carve((size_t)N * 4);
  char* zero_end = p;
  int* offs_s = (int*)carve((size_t)(N + 1) * 4);
  int* offs_k = (int*)carve((size_t)(N + 1) * 4);
  int* bsum   = (int*)carve(4096);
  int* csr_s  = (int*)carve((size_t)E * 4);
  int* csr_k  = (int*)carve((size_t)EK * 4);
  _Float16* Wh  = (_Float16*)carve((size_t)3 * HID * F_IN * 2);
  _Float16* gS1 = (_Float16*)carve((size_t)N * HID * 2);
  _Float16* gS2 = (_Float16*)carve((size_t)N * HID * 2);
  _Float16* gF2s= (_Float16*)carve((size_t)N * HID * 2);
  _Float16* gF2k= (_Float16*)carve((size_t)N * HID * 2);
  _Float16* tS2 = (_Float16*)carve((size_t)N * HID * 2);

  float* out_h0 = (float*)d_out;
  float* out_h1 = out_h0 + (size_t)N * HID;
  float* out_z0 = out_h1 + (size_t)N * HID;
  float* out_z1 = out_z0 + (size_t)N * HID;
  // z1 region (fp32, N*HID floats = 2x fp16 buffers) is free until the very last
  // launch -> scratch for the two single-use step-1 outputs.
  _Float16* tS1 = (_Float16*)out_z1;
  _Float16* tF2 = tS1 + (size_t)N * HID;

  hipMemsetAsync(d_ws, 0, (size_t)(zero_end - (char*)d_ws), stream);

  const int tpb = 256;
  int etot = E + EK;
  k_count2<<<(etot + tpb - 1) / tpb, tpb, 0, stream>>>(col_s, E, cnt_s, col_k, EK, cnt_k);

  int nb = (N + 1023) / 1024;
  k_scan_block<<<nb, 1024, 0, stream>>>(cnt_s, N, offs_s, bsum);
  k_scan_single<<<1, 64, 0, stream>>>(bsum, nb, offs_s + N);
  k_add_off<<<(N + tpb - 1) / tpb, tpb, 0, stream>>>(offs_s, bsum, N);
  k_scan_block<<<nb, 1024, 0, stream>>>(cnt_k, N, offs_k, bsum);
  k_scan_single<<<1, 64, 0, stream>>>(bsum, nb, offs_k + N);
  k_add_off<<<(N + tpb - 1) / tpb, tpb, 0, stream>>>(offs_k, bsum, N);

  k_scatter2<<<(etot + tpb - 1) / tpb, tpb, 0, stream>>>(
      row_s, col_s, E, offs_s, cur_s, csr_s,
      row_k, col_k, EK, offs_k, cur_k, csr_k);

  k_cvt_w<<<96, 256, 0, stream>>>(W_s1, W_s2, W_f2, Wh);
  k_gemm3<<<(N + 31) / 32, 256, 0, stream>>>(x, Wh, b_s1, b_s2, b_f2, N, cnt_s, cnt_k,
                                             gS1, gS2, gF2s, gF2k);

  int spmm_grid = (N + 3) / 4;

  // step 1 (all chains), step 2 (s1 & f2 finalize, s2 continues)
  k_spmm3<<<spmm_grid, 256, 0, stream>>>((const unsigned int*)gS1, (const unsigned int*)gS2,
                                         (const unsigned int*)gF2s,
                                         tS1, tS2, tF2, 0, 0, 0,
                                         csr_s, offs_s, cnt_s, N);
  k_spmm3<<<spmm_grid, 256, 0, stream>>>((const unsigned int*)tS1, (const unsigned int*)tS2,
                                         (const unsigned int*)tF2,
                                         out_h0, gS1, out_z0, 1, 0, 1,
                                         csr_s, offs_s, cnt_s, N);

  // s2 steps 3..10: ping-pong gS1 <-> tS2
  {
    _Float16* cur = gS1; _Float16* alt = tS2;
    for (int it = 0; it < 7; ++it) {
      k_spmm_h<<<spmm_grid, 256, 0, stream>>>((const unsigned int*)cur, alt,
                                              csr_s, offs_s, cnt_s, N, 0, nullptr);
      _Float16* t = cur; cur = alt; alt = t;
    }
    k_spmm_h<<<spmm_grid, 256, 0, stream>>>((const unsigned int*)cur, out_h1,
                                            csr_s, offs_s, cnt_s, N, 1, nullptr);
  }

  // knn step (last: frees the z1 scratch region before writing it)
  k_spmm_h<<<spmm_grid, 256, 0, stream>>>((const unsigned int*)gF2k, out_z1,
                                          csr_k, offs_k, cnt_k, N, 2,
                                          (const float2*)out_z0);
}

// Round 7
// 713.616 us; speedup vs baseline: 1.0170x; 1.0170x over previous
//
#include <hip/hip_runtime.h>
#include <hip/hip_fp16.h>

#define F_IN 256
#define HID 128

typedef _Float16 half8 __attribute__((ext_vector_type(8)));
typedef _Float16 half4v __attribute__((ext_vector_type(4)));
typedef float f32x4 __attribute__((ext_vector_type(4)));
typedef unsigned int uint4v __attribute__((ext_vector_type(4)));

// ---------------- graph preprocessing ----------------

__global__ void k_count2(const int* __restrict__ col_s, int E, int* __restrict__ cnt_s,
                         const int* __restrict__ col_k, int EK, int* __restrict__ cnt_k) {
  int e = blockIdx.x * blockDim.x + threadIdx.x;
  if (e < E) {
    atomicAdd(&cnt_s[col_s[e]], 1);
  } else {
    int f = e - E;
    if (f < EK) atomicAdd(&cnt_k[col_k[f]], 1);
  }
}

__global__ void k_scan_block(const int* __restrict__ in, int n, int* __restrict__ out,
                             int* __restrict__ bsum) {
  __shared__ int s[1024];
  int tid = threadIdx.x;
  int i = blockIdx.x * 1024 + tid;
  int v = (i < n) ? in[i] : 0;
  s[tid] = v;
  __syncthreads();
  for (int off = 1; off < 1024; off <<= 1) {
    int t = (tid >= off) ? s[tid - off] : 0;
    __syncthreads();
    s[tid] += t;
    __syncthreads();
  }
  if (i < n) out[i] = s[tid] - v;          // exclusive
  if (tid == 1023) bsum[blockIdx.x] = s[1023];
}

__global__ void k_scan_single(int* __restrict__ bsum, int nb, int* __restrict__ tail) {
  if (threadIdx.x == 0 && blockIdx.x == 0) {
    int run = 0;
    for (int b = 0; b < nb; ++b) { int t = bsum[b]; bsum[b] = run; run += t; }
    *tail = run;
  }
}

__global__ void k_add_off(int* __restrict__ out, const int* __restrict__ bsum, int n) {
  int i = blockIdx.x * blockDim.x + threadIdx.x;
  if (i < n) out[i] += bsum[i >> 10];
}

__global__ void k_scatter2(const int* __restrict__ row_s, const int* __restrict__ col_s, int E,
                           const int* __restrict__ offs_s, int* __restrict__ cur_s,
                           int* __restrict__ csr_s,
                           const int* __restrict__ row_k, const int* __restrict__ col_k, int EK,
                           const int* __restrict__ offs_k, int* __restrict__ cur_k,
                           int* __restrict__ csr_k) {
  int e = blockIdx.x * blockDim.x + threadIdx.x;
  if (e < E) {
    int c = col_s[e];
    int p = offs_s[c] + atomicAdd(&cur_s[c], 1);
    csr_s[p] = row_s[e];
  } else {
    int f = e - E;
    if (f < EK) {
      int c = col_k[f];
      int p = offs_k[c] + atomicAdd(&cur_k[c], 1);
      csr_k[p] = row_k[f];
    }
  }
}

// ---------------- W fp32 -> fp16 (all three, concatenated) ----------------

__global__ void k_cvt_w(const float* __restrict__ W0, const float* __restrict__ W1,
                        const float* __restrict__ W2, _Float16* __restrict__ Wh) {
  const int sz = HID * F_IN;                    // 32768
  int idx = (blockIdx.x * 256 + threadIdx.x) * 4;  // [0, 3*sz)
  const float* src = (idx < sz) ? (W0 + idx)
                   : (idx < 2 * sz) ? (W1 + idx - sz)
                   : (W2 + idx - 2 * sz);
  float4 v = *(const float4*)src;
  half4v o;
  o[0] = (_Float16)v.x; o[1] = (_Float16)v.y; o[2] = (_Float16)v.z; o[3] = (_Float16)v.w;
  *(half4v*)(Wh + idx) = o;
}

// ---------------- fused MFMA GEMM, LDS-tiled, write-coalesced, pipelined ----------------
// Block = 32 nodes, 4 waves. Wave (mh,ch) owns 16 nodes x 64 contiguous cols
// (full-line writes). launch_bounds(256,6): VGPR cap 84 (round 6's (256,8) gave
// VGPR=32 -> no load window -> latency-bound). Explicit 1-deep prefetch (xfn/wfn).

__global__ __launch_bounds__(256, 6) void k_gemm3(
    const float* __restrict__ x, const _Float16* __restrict__ Wh,
    const float* __restrict__ b0, const float* __restrict__ b1, const float* __restrict__ b2,
    int n, const int* __restrict__ cnt_s, const int* __restrict__ cnt_k,
    _Float16* __restrict__ gS1, _Float16* __restrict__ gS2,
    _Float16* __restrict__ gF2s, _Float16* __restrict__ gF2k)
{
  __shared__ _Float16 xs[32 * F_IN];       // 16 KB, swizzled
  int tid = threadIdx.x;
  int m0 = blockIdx.x * 32;

  // ---- stage x tile: thread t -> row t>>3, cols [(t&7)*32, +32) ----
  {
    int r = tid >> 3;
    int cbase = (tid & 7) * 32;
    int gr = m0 + r; if (gr >= n) gr = n - 1;
    const float* src = x + (size_t)gr * F_IN + cbase;
    unsigned sw = (unsigned)((r & 7) << 4);
    char* drow = (char*)xs + r * (F_IN * 2);
#pragma unroll
    for (int i = 0; i < 4; ++i) {          // 4 x 16B blocks = 32 fp16
      float4 a = *(const float4*)(src + i * 8);
      float4 b = *(const float4*)(src + i * 8 + 4);
      half8 v;
      v[0] = (_Float16)a.x; v[1] = (_Float16)a.y; v[2] = (_Float16)a.z; v[3] = (_Float16)a.w;
      v[4] = (_Float16)b.x; v[5] = (_Float16)b.y; v[6] = (_Float16)b.z; v[7] = (_Float16)b.w;
      *(half8*)(drow + (((unsigned)(cbase * 2 + i * 16)) ^ sw)) = v;
    }
  }
  __syncthreads();

  int lane = tid & 63;
  int wv = tid >> 6;
  int mh = wv >> 1, ch = wv & 1;            // m-half (16 nodes), col-half (64 cols)
  int l15 = lane & 15, lhi = lane >> 4;
  int rloc = mh * 16 + l15;
  unsigned swr = (unsigned)((rloc & 7) << 4);
  const char* xrow = (const char*)xs + rloc * (F_IN * 2);

  int node = m0 + rloc;
  int cn = (node < n) ? node : (n - 1);
  float ss = rsqrtf((float)(cnt_s[cn] + 1));
  float sk = rsqrtf((float)(cnt_k[cn] + 1));

#pragma unroll 1
  for (int w = 0; w < 3; ++w) {
    const float* bias = (w == 0) ? b0 : (w == 1) ? b1 : b2;
    _Float16* dst = (w == 0) ? gS1 : (w == 1) ? gS2 : gF2s;
    const _Float16* Wp = Wh + (size_t)w * HID * F_IN
                            + (size_t)(ch * 64 + l15) * F_IN + lhi * 8;

    f32x4 acc[4];
#pragma unroll
    for (int nt = 0; nt < 4; ++nt) {
      float4 bv = *(const float4*)(bias + ch * 64 + nt * 16 + lhi * 4);
      acc[nt] = (f32x4){bv.x, bv.y, bv.z, bv.w};
    }

    // prologue: kt = 0 operands
    half8 xf = *(const half8*)(xrow + (((unsigned)((0 * 32 + lhi * 8) * 2)) ^ swr));
    half8 wf[4];
#pragma unroll
    for (int nt = 0; nt < 4; ++nt)
      wf[nt] = *(const half8*)(Wp + (size_t)nt * 16 * F_IN + 0 * 32);

#pragma unroll
    for (int kt = 0; kt < 8; ++kt) {
      half8 xfn; half8 wfn[4];
      if (kt < 7) {
        xfn = *(const half8*)(xrow + (((unsigned)(((kt + 1) * 32 + lhi * 8) * 2)) ^ swr));
#pragma unroll
        for (int nt = 0; nt < 4; ++nt)
          wfn[nt] = *(const half8*)(Wp + (size_t)nt * 16 * F_IN + (kt + 1) * 32);
      }
#pragma unroll
      for (int nt = 0; nt < 4; ++nt)
        acc[nt] = __builtin_amdgcn_mfma_f32_16x16x32_f16(wf[nt], xf, acc[nt], 0, 0, 0);
      if (kt < 7) {
        xf = xfn;
#pragma unroll
        for (int nt = 0; nt < 4; ++nt) wf[nt] = wfn[nt];
      }
    }

    if (node < n) {
      size_t obase = (size_t)node * HID + ch * 64 + lhi * 4;
#pragma unroll
      for (int nt = 0; nt < 4; ++nt) {
        half4v o;
        o[0] = (_Float16)(acc[nt][0] * ss); o[1] = (_Float16)(acc[nt][1] * ss);
        o[2] = (_Float16)(acc[nt][2] * ss); o[3] = (_Float16)(acc[nt][3] * ss);
        *(half4v*)(dst + obase + nt * 16) = o;
      }
      if (w == 2) {
#pragma unroll
        for (int nt = 0; nt < 4; ++nt) {
          half4v o2;
          o2[0] = (_Float16)(acc[nt][0] * sk); o2[1] = (_Float16)(acc[nt][1] * sk);
          o2[2] = (_Float16)(acc[nt][2] * sk); o2[3] = (_Float16)(acc[nt][3] * sk);
          *(half4v*)(gF2k + obase + nt * 16) = o2;
        }
      }
    }
  }
}

// ---------------- SpMM (fp16 features, 16B/lane gathers) ----------------
// One wave per dest node. Lane layout: g = lane>>4 (edge sub-slot 0..3),
// c = lane&15 (16B chunk = 8 halves of the 256B row). One dwordx4 instruction
// gathers 4 edges' full rows (1 KB) -> 4x fewer gather instructions than
// dword/lane. Cross-g reduce: shfl_xor 16, 32. Self row added post-reduce.
// mode 0: *1/deg -> fp16; mode 1: *rsqrt(deg) -> fp32; mode 2: mode1 + addsrc.

__device__ inline float2 h2f2(unsigned int u) {
  __half2 h; *(unsigned int*)&h = u; return __half22float2(h);
}

__global__ __launch_bounds__(256) void k_spmm_h(
    const _Float16* __restrict__ gin, void* __restrict__ gout,
    const int* __restrict__ csr, const int* __restrict__ offs, const int* __restrict__ cnt,
    int n, int mode, const float* __restrict__ addsrc)
{
  int w = (blockIdx.x << 2) | ((int)threadIdx.x >> 6);
  if (w >= n) return;
  int lane = threadIdx.x & 63;
  int g = lane >> 4;
  int c = lane & 15;
  int beg = offs[w], end = offs[w + 1];

  float acc[8];
#pragma unroll
  for (int i = 0; i < 8; ++i) acc[i] = 0.f;

  int e = beg;
#pragma unroll 1
  for (; e + 16 <= end; e += 16) {
    int idx[4];
#pragma unroll
    for (int j = 0; j < 4; ++j) idx[j] = csr[e + 4 * j + g];
    uint4v u[4];
#pragma unroll
    for (int j = 0; j < 4; ++j)
      u[j] = *(const uint4v*)(gin + ((size_t)(unsigned)idx[j] << 7) + c * 8);
#pragma unroll
    for (int j = 0; j < 4; ++j)
#pragma unroll
      for (int q = 0; q < 4; ++q) {
        float2 v = h2f2(u[j][q]);
        acc[q * 2] += v.x; acc[q * 2 + 1] += v.y;
      }
  }
#pragma unroll 1
  for (; e + 4 <= end; e += 4) {
    int idx = csr[e + g];
    uint4v u = *(const uint4v*)(gin + ((size_t)(unsigned)idx << 7) + c * 8);
#pragma unroll
    for (int q = 0; q < 4; ++q) {
      float2 v = h2f2(u[q]);
      acc[q * 2] += v.x; acc[q * 2 + 1] += v.y;
    }
  }
  {
    int rem = end - e;
    if (g < rem) {
      int idx = csr[e + g];
      uint4v u = *(const uint4v*)(gin + ((size_t)(unsigned)idx << 7) + c * 8);
#pragma unroll
      for (int q = 0; q < 4; ++q) {
        float2 v = h2f2(u[q]);
        acc[q * 2] += v.x; acc[q * 2 + 1] += v.y;
      }
    }
  }
  // reduce across the 4 g-groups
#pragma unroll
  for (int i = 0; i < 8; ++i) {
    acc[i] += __shfl_xor(acc[i], 16, 64);
    acc[i] += __shfl_xor(acc[i], 32, 64);
  }
  // self loop
  {
    uint4v u = *(const uint4v*)(gin + ((size_t)w << 7) + c * 8);
#pragma unroll
    for (int q = 0; q < 4; ++q) {
      float2 v = h2f2(u[q]);
      acc[q * 2] += v.x; acc[q * 2 + 1] += v.y;
    }
  }

  float deg = (float)(cnt[w] + 1);
  if (mode == 0) {
    float sc = 1.0f / deg;
    if (g == 0) {
      uint4v o;
#pragma unroll
      for (int q = 0; q < 4; ++q) {
        __half2 h = __float22half2_rn(make_float2(acc[q * 2] * sc, acc[q * 2 + 1] * sc));
        o[q] = *(unsigned int*)&h;
      }
      *(uint4v*)((_Float16*)gout + ((size_t)w << 7) + c * 8) = o;
    }
  } else {
    float sc = rsqrtf(deg);
    if (g == 0) {
      float o[8];
#pragma unroll
      for (int i = 0; i < 8; ++i) o[i] = acc[i] * sc;
      if (mode == 2) {
        const float* ap = addsrc + ((size_t)w << 7) + c * 8;
        float4 a0 = *(const float4*)ap;
        float4 a1 = *(const float4*)(ap + 4);
        o[0] += a0.x; o[1] += a0.y; o[2] += a0.z; o[3] += a0.w;
        o[4] += a1.x; o[5] += a1.y; o[6] += a1.z; o[7] += a1.w;
      }
      float* op = (float*)gout + ((size_t)w << 7) + c * 8;
      *(float4*)op = make_float4(o[0], o[1], o[2], o[3]);
      *(float4*)(op + 4) = make_float4(o[4], o[5], o[6], o[7]);
    }
  }
}

// 3 feature matrices propagated in one pass over the graph (shared steps 1,2)
__global__ __launch_bounds__(256) void k_spmm3(
    const _Float16* __restrict__ g0, const _Float16* __restrict__ g1,
    const _Float16* __restrict__ g2,
    void* __restrict__ o0, void* __restrict__ o1, void* __restrict__ o2,
    int md0, int md1, int md2,
    const int* __restrict__ csr, const int* __restrict__ offs, const int* __restrict__ cnt,
    int n)
{
  int w = (blockIdx.x << 2) | ((int)threadIdx.x >> 6);
  if (w >= n) return;
  int lane = threadIdx.x & 63;
  int g = lane >> 4;
  int c = lane & 15;
  int beg = offs[w], end = offs[w + 1];

  float a0[8], a1[8], a2[8];
#pragma unroll
  for (int i = 0; i < 8; ++i) { a0[i] = 0.f; a1[i] = 0.f; a2[i] = 0.f; }

  int e = beg;
#pragma unroll 1
  for (; e + 4 <= end; e += 4) {
    size_t off = ((size_t)(unsigned)csr[e + g] << 7) + c * 8;
    uint4v u0 = *(const uint4v*)(g0 + off);
    uint4v u1 = *(const uint4v*)(g1 + off);
    uint4v u2 = *(const uint4v*)(g2 + off);
#pragma unroll
    for (int q = 0; q < 4; ++q) {
      float2 v;
      v = h2f2(u0[q]); a0[q * 2] += v.x; a0[q * 2 + 1] += v.y;
      v = h2f2(u1[q]); a1[q * 2] += v.x; a1[q * 2 + 1] += v.y;
      v = h2f2(u2[q]); a2[q * 2] += v.x; a2[q * 2 + 1] += v.y;
    }
  }
  {
    int rem = end - e;
    if (g < rem) {
      size_t off = ((size_t)(unsigned)csr[e + g] << 7) + c * 8;
      uint4v u0 = *(const uint4v*)(g0 + off);
      uint4v u1 = *(const uint4v*)(g1 + off);
      uint4v u2 = *(const uint4v*)(g2 + off);
#pragma unroll
      for (int q = 0; q < 4; ++q) {
        float2 v;
        v = h2f2(u0[q]); a0[q * 2] += v.x; a0[q * 2 + 1] += v.y;
        v = h2f2(u1[q]); a1[q * 2] += v.x; a1[q * 2 + 1] += v.y;
        v = h2f2(u2[q]); a2[q * 2] += v.x; a2[q * 2 + 1] += v.y;
      }
    }
  }
#pragma unroll
  for (int i = 0; i < 8; ++i) {
    a0[i] += __shfl_xor(a0[i], 16, 64); a0[i] += __shfl_xor(a0[i], 32, 64);
    a1[i] += __shfl_xor(a1[i], 16, 64); a1[i] += __shfl_xor(a1[i], 32, 64);
    a2[i] += __shfl_xor(a2[i], 16, 64); a2[i] += __shfl_xor(a2[i], 32, 64);
  }
  // self loops
  {
    size_t off = ((size_t)w << 7) + c * 8;
    uint4v u0 = *(const uint4v*)(g0 + off);
    uint4v u1 = *(const uint4v*)(g1 + off);
    uint4v u2 = *(const uint4v*)(g2 + off);
#pragma unroll
    for (int q = 0; q < 4; ++q) {
      float2 v;
      v = h2f2(u0[q]); a0[q * 2] += v.x; a0[q * 2 + 1] += v.y;
      v = h2f2(u1[q]); a1[q * 2] += v.x; a1[q * 2 + 1] += v.y;
      v = h2f2(u2[q]); a2[q * 2] += v.x; a2[q * 2 + 1] += v.y;
    }
  }

  float deg = (float)(cnt[w] + 1);
  if (g == 0) {
    float inv = 1.0f / deg, rs = rsqrtf(deg);
    // matrix 0
    {
      float sc = (md0 == 0) ? inv : rs;
      if (md0 == 0) {
        uint4v o;
#pragma unroll
        for (int q = 0; q < 4; ++q) {
          __half2 h = __float22half2_rn(make_float2(a0[q * 2] * sc, a0[q * 2 + 1] * sc));
          o[q] = *(unsigned int*)&h;
        }
        *(uint4v*)((_Float16*)o0 + ((size_t)w << 7) + c * 8) = o;
      } else {
        float* op = (float*)o0 + ((size_t)w << 7) + c * 8;
        *(float4*)op = make_float4(a0[0] * sc, a0[1] * sc, a0[2] * sc, a0[3] * sc);
        *(float4*)(op + 4) = make_float4(a0[4] * sc, a0[5] * sc, a0[6] * sc, a0[7] * sc);
      }
    }
    // matrix 1
    {
      float sc = (md1 == 0) ? inv : rs;
      if (md1 == 0) {
        uint4v o;
#pragma unroll
        for (int q = 0; q < 4; ++q) {
          __half2 h = __float22half2_rn(make_float2(a1[q * 2] * sc, a1[q * 2 + 1] * sc));
          o[q] = *(unsigned int*)&h;
        }
        *(uint4v*)((_Float16*)o1 + ((size_t)w << 7) + c * 8) = o;
      } else {
        float* op = (float*)o1 + ((size_t)w << 7) + c * 8;
        *(float4*)op = make_float4(a1[0] * sc, a1[1] * sc, a1[2] * sc, a1[3] * sc);
        *(float4*)(op + 4) = make_float4(a1[4] * sc, a1[5] * sc, a1[6] * sc, a1[7] * sc);
      }
    }
    // matrix 2
    {
      float sc = (md2 == 0) ? inv : rs;
      if (md2 == 0) {
        uint4v o;
#pragma unroll
        for (int q = 0; q < 4; ++q) {
          __half2 h = __float22half2_rn(make_float2(a2[q * 2] * sc, a2[q * 2 + 1] * sc));
          o[q] = *(unsigned int*)&h;
        }
        *(uint4v*)((_Float16*)o2 + ((size_t)w << 7) + c * 8) = o;
      } else {
        float* op = (float*)o2 + ((size_t)w << 7) + c * 8;
        *(float4*)op = make_float4(a2[0] * sc, a2[1] * sc, a2[2] * sc, a2[3] * sc);
        *(float4*)(op + 4) = make_float4(a2[4] * sc, a2[5] * sc, a2[6] * sc, a2[7] * sc);
      }
    }
  }
}

// ---------------- launch ----------------

extern "C" void kernel_launch(void* const* d_in, const int* in_sizes, int n_in,
                              void* d_out, int out_size, void* d_ws, size_t ws_size,
                              hipStream_t stream) {
  const float* x    = (const float*)d_in[0];
  const int*   ei   = (const int*)d_in[1];
  const int*   knn  = (const int*)d_in[2];
  const float* W_s1 = (const float*)d_in[3];
  const float* b_s1 = (const float*)d_in[4];
  const float* W_s2 = (const float*)d_in[5];
  const float* b_s2 = (const float*)d_in[6];
  const float* W_f2 = (const float*)d_in[7];
  const float* b_f2 = (const float*)d_in[8];

  const int N  = in_sizes[0] / F_IN;
  const int E  = in_sizes[1] / 2;
  const int EK = in_sizes[2] / 2;
  const int* row_s = ei;   const int* col_s = ei + E;
  const int* row_k = knn;  const int* col_k = knn + EK;

  char* p = (char*)d_ws;
  auto carve = [&](size_t bytes) {
    char* r = p; p += (bytes + 511) & ~(size_t)511; return (void*)r;
  };
  int* cnt_s = (int*)carve((size_t)N * 4);
  int* cnt_k = (int*)carve((size_t)N * 4);
  int* cur_s = (int*)carve((size_t)N * 4);
  int* cur_k = (int*)carve((size_t)N * 4);
  char* zero_end = p;
  int* offs_s = (int*)carve((size_t)(N + 1) * 4);
  int* offs_k = (int*)carve((size_t)(N + 1) * 4);
  int* bsum   = (int*)carve(4096);
  int* csr_s  = (int*)carve((size_t)E * 4);
  int* csr_k  = (int*)carve((size_t)EK * 4);
  _Float16* Wh  = (_Float16*)carve((size_t)3 * HID * F_IN * 2);
  _Float16* gS1 = (_Float16*)carve((size_t)N * HID * 2);
  _Float16* gS2 = (_Float16*)carve((size_t)N * HID * 2);
  _Float16* gF2s= (_Float16*)carve((size_t)N * HID * 2);
  _Float16* gF2k= (_Float16*)carve((size_t)N * HID * 2);
  _Float16* tS2 = (_Float16*)carve((size_t)N * HID * 2);

  float* out_h0 = (float*)d_out;
  float* out_h1 = out_h0 + (size_t)N * HID;
  float* out_z0 = out_h1 + (size_t)N * HID;
  float* out_z1 = out_z0 + (size_t)N * HID;
  // z1 region (fp32, N*HID floats = 2x fp16 buffers) is free until the very last
  // launch -> scratch for the two single-use step-1 outputs.
  _Float16* tS1 = (_Float16*)out_z1;
  _Float16* tF2 = tS1 + (size_t)N * HID;

  hipMemsetAsync(d_ws, 0, (size_t)(zero_end - (char*)d_ws), stream);

  const int tpb = 256;
  int etot = E + EK;
  k_count2<<<(etot + tpb - 1) / tpb, tpb, 0, stream>>>(col_s, E, cnt_s, col_k, EK, cnt_k);

  int nb = (N + 1023) / 1024;
  k_scan_block<<<nb, 1024, 0, stream>>>(cnt_s, N, offs_s, bsum);
  k_scan_single<<<1, 64, 0, stream>>>(bsum, nb, offs_s + N);
  k_add_off<<<(N + tpb - 1) / tpb, tpb, 0, stream>>>(offs_s, bsum, N);
  k_scan_block<<<nb, 1024, 0, stream>>>(cnt_k, N, offs_k, bsum);
  k_scan_single<<<1, 64, 0, stream>>>(bsum, nb, offs_k + N);
  k_add_off<<<(N + tpb - 1) / tpb, tpb, 0, stream>>>(offs_k, bsum, N);

  k_scatter2<<<(etot + tpb - 1) / tpb, tpb, 0, stream>>>(
      row_s, col_s, E, offs_s, cur_s, csr_s,
      row_k, col_k, EK, offs_k, cur_k, csr_k);

  k_cvt_w<<<96, 256, 0, stream>>>(W_s1, W_s2, W_f2, Wh);
  k_gemm3<<<(N + 31) / 32, 256, 0, stream>>>(x, Wh, b_s1, b_s2, b_f2, N, cnt_s, cnt_k,
                                             gS1, gS2, gF2s, gF2k);

  int spmm_grid = (N + 3) / 4;

  // step 1 (all chains), step 2 (s1 & f2 finalize, s2 continues)
  k_spmm3<<<spmm_grid, 256, 0, stream>>>(gS1, gS2, gF2s,
                                         tS1, tS2, tF2, 0, 0, 0,
                                         csr_s, offs_s, cnt_s, N);
  k_spmm3<<<spmm_grid, 256, 0, stream>>>(tS1, tS2, tF2,
                                         out_h0, gS1, out_z0, 1, 0, 1,
                                         csr_s, offs_s, cnt_s, N);

  // s2 steps 3..10: ping-pong gS1 <-> tS2
  {
    _Float16* cur = gS1; _Float16* alt = tS2;
    for (int it = 0; it < 7; ++it) {
      k_spmm_h<<<spmm_grid, 256, 0, stream>>>(cur, alt,
                                              csr_s, offs_s, cnt_s, N, 0, nullptr);
      _Float16* t = cur; cur = alt; alt = t;
    }
    k_spmm_h<<<spmm_grid, 256, 0, stream>>>(cur, out_h1,
                                            csr_s, offs_s, cnt_s, N, 1, nullptr);
  }

  // knn step (last: frees the z1 scratch region before writing it)
  k_spmm_h<<<spmm_grid, 256, 0, stream>>>(gF2k, out_z1,
                                          csr_k, offs_k, cnt_k, N, 2,
                                          out_z0);
}

// Round 8
// 658.382 us; speedup vs baseline: 1.1023x; 1.0839x over previous
//
#include <hip/hip_runtime.h>
#include <hip/hip_fp16.h>

#define F_IN 256
#define HID 128

typedef _Float16 half8 __attribute__((ext_vector_type(8)));
typedef _Float16 half4v __attribute__((ext_vector_type(4)));
typedef float f32x4 __attribute__((ext_vector_type(4)));
typedef unsigned int uint4v __attribute__((ext_vector_type(4)));

// ---------------- graph preprocessing ----------------

__global__ void k_count2(const int* __restrict__ col_s, int E, int* __restrict__ cnt_s,
                         const int* __restrict__ col_k, int EK, int* __restrict__ cnt_k) {
  int e = blockIdx.x * blockDim.x + threadIdx.x;
  if (e < E) {
    atomicAdd(&cnt_s[col_s[e]], 1);
  } else {
    int f = e - E;
    if (f < EK) atomicAdd(&cnt_k[col_k[f]], 1);
  }
}

__global__ void k_scan_block(const int* __restrict__ in, int n, int* __restrict__ out,
                             int* __restrict__ bsum) {
  __shared__ int s[1024];
  int tid = threadIdx.x;
  int i = blockIdx.x * 1024 + tid;
  int v = (i < n) ? in[i] : 0;
  s[tid] = v;
  __syncthreads();
  for (int off = 1; off < 1024; off <<= 1) {
    int t = (tid >= off) ? s[tid - off] : 0;
    __syncthreads();
    s[tid] += t;
    __syncthreads();
  }
  if (i < n) out[i] = s[tid] - v;          // exclusive
  if (tid == 1023) bsum[blockIdx.x] = s[1023];
}

__global__ void k_scan_single(int* __restrict__ bsum, int nb, int* __restrict__ tail) {
  if (threadIdx.x == 0 && blockIdx.x == 0) {
    int run = 0;
    for (int b = 0; b < nb; ++b) { int t = bsum[b]; bsum[b] = run; run += t; }
    *tail = run;
  }
}

__global__ void k_add_off(int* __restrict__ out, const int* __restrict__ bsum, int n) {
  int i = blockIdx.x * blockDim.x + threadIdx.x;
  if (i < n) out[i] += bsum[i >> 10];
}

__global__ void k_scatter2(const int* __restrict__ row_s, const int* __restrict__ col_s, int E,
                           const int* __restrict__ offs_s, int* __restrict__ cur_s,
                           int* __restrict__ csr_s,
                           const int* __restrict__ row_k, const int* __restrict__ col_k, int EK,
                           const int* __restrict__ offs_k, int* __restrict__ cur_k,
                           int* __restrict__ csr_k) {
  int e = blockIdx.x * blockDim.x + threadIdx.x;
  if (e < E) {
    int c = col_s[e];
    int p = offs_s[c] + atomicAdd(&cur_s[c], 1);
    csr_s[p] = row_s[e];
  } else {
    int f = e - E;
    if (f < EK) {
      int c = col_k[f];
      int p = offs_k[c] + atomicAdd(&cur_k[c], 1);
      csr_k[p] = row_k[f];
    }
  }
}

// ---------------- W fp32 -> fp16 (all three, concatenated) ----------------

__global__ void k_cvt_w(const float* __restrict__ W0, const float* __restrict__ W1,
                        const float* __restrict__ W2, _Float16* __restrict__ Wh) {
  const int sz = HID * F_IN;                    // 32768
  int idx = (blockIdx.x * 256 + threadIdx.x) * 4;  // [0, 3*sz)
  const float* src = (idx < sz) ? (W0 + idx)
                   : (idx < 2 * sz) ? (W1 + idx - sz)
                   : (W2 + idx - 2 * sz);
  float4 v = *(const float4*)src;
  half4v o;
  o[0] = (_Float16)v.x; o[1] = (_Float16)v.y; o[2] = (_Float16)v.z; o[3] = (_Float16)v.w;
  *(half4v*)(Wh + idx) = o;
}

// ---------------- fused MFMA GEMM, m97-style LDS double-buffered ----------------
// Block = 64 nodes x 128 cols (one W per w-iter, 3 iters). BK=64, dbuf LDS:
// A 2x8KB + B 2x16KB = 48KB -> 3 blocks/CU. 4 waves (2M x 2N), wave tile 32x64,
// acc 2x4 f32x4 = 32 VGPR. Staging: reg-load (x: fp32->fp16 cvt) + XOR-swizzled
// ds_write_b128; compute: swizzled ds_read_b128 + MFMA (compiler pipelines LDS
// feeds well - m97 evidence). One barrier per K-step; next loads issued early.

__device__ inline half8 cvt8(float4 a, float4 b) {
  half8 v;
  v[0] = (_Float16)a.x; v[1] = (_Float16)a.y; v[2] = (_Float16)a.z; v[3] = (_Float16)a.w;
  v[4] = (_Float16)b.x; v[5] = (_Float16)b.y; v[6] = (_Float16)b.z; v[7] = (_Float16)b.w;
  return v;
}

__global__ __launch_bounds__(256, 3) void k_gemm3(
    const float* __restrict__ x, const _Float16* __restrict__ Wh,
    const float* __restrict__ b0, const float* __restrict__ b1, const float* __restrict__ b2,
    int n, const int* __restrict__ cnt_s, const int* __restrict__ cnt_k,
    _Float16* __restrict__ gS1, _Float16* __restrict__ gS2,
    _Float16* __restrict__ gF2s, _Float16* __restrict__ gF2k)
{
  __shared__ __align__(16) char lds[49152];  // A0@0 A1@8192 B0@16384 B1@32768
  int tid = threadIdx.x;
  int m0 = blockIdx.x * 64;

  // ---- staging address precompute ----
  // A: thread -> row tid>>2 (of 64), chunks {(tid&3)*2, +1} of 8 (16B fp16 each)
  int rA = tid >> 2;
  int cA0 = (tid & 3) * 2, cA1 = cA0 + 1;
  int gnA = m0 + rA; if (gnA >= n) gnA = n - 1;
  const float* xA = x + (size_t)gnA * F_IN;
  unsigned aw0 = (unsigned)(rA * 128 + ((cA0 ^ (rA & 7)) << 4));
  unsigned aw1 = (unsigned)(rA * 128 + ((cA1 ^ (rA & 7)) << 4));
  // B: thread -> row tid>>1 (of 128), chunks (tid&1)*4 .. +3
  int rB = tid >> 1;
  int cB0 = (tid & 1) * 4;
  unsigned bw[4];
#pragma unroll
  for (int i = 0; i < 4; ++i)
    bw[i] = (unsigned)(rB * 128 + (((cB0 + i) ^ (rB & 7)) << 4));

  // ---- compute-side ids ----
  int lane = tid & 63;
  int wv = tid >> 6;
  int wm = wv >> 1, wn = wv & 1;           // wave tile: rows wm*32+32, cols wn*64+64
  int l15 = lane & 15, lhi = lane >> 4;
  unsigned koff0 = (unsigned)(((0 * 4 + lhi) ^ (l15 & 7)) << 4);
  unsigned koff1 = (unsigned)(((1 * 4 + lhi) ^ (l15 & 7)) << 4);
  unsigned raw0 = (unsigned)((wm * 32 + 0 * 16 + l15) * 128);
  unsigned raw1 = (unsigned)((wm * 32 + 1 * 16 + l15) * 128);
  unsigned rbw[4];
#pragma unroll
  for (int ni = 0; ni < 4; ++ni)
    rbw[ni] = (unsigned)((wn * 64 + ni * 16 + l15) * 128);

  // per-node scales (independent of w)
  int nodebase = m0 + wm * 32 + l15;
  float ss[2], sk[2];
#pragma unroll
  for (int mi = 0; mi < 2; ++mi) {
    int nd = nodebase + mi * 16;
    int cn = (nd < n) ? nd : (n - 1);
    ss[mi] = rsqrtf((float)(cnt_s[cn] + 1));
    sk[mi] = rsqrtf((float)(cnt_k[cn] + 1));
  }

#pragma unroll 1
  for (int w = 0; w < 3; ++w) {
    const float* bias = (w == 0) ? b0 : (w == 1) ? b1 : b2;
    _Float16* dst = (w == 0) ? gS1 : (w == 1) ? gS2 : gF2s;
    const _Float16* WB = Wh + (size_t)w * (HID * F_IN) + (size_t)rB * F_IN;

    f32x4 acc[2][4];
#pragma unroll
    for (int ni = 0; ni < 4; ++ni) {
      float4 bv = *(const float4*)(bias + wn * 64 + ni * 16 + lhi * 4);
      f32x4 b4 = {bv.x, bv.y, bv.z, bv.w};
      acc[0][ni] = b4; acc[1][ni] = b4;
    }

    float4 fa[4]; uint4v ub[4];
    // LD(0)
    fa[0] = *(const float4*)(xA + 0 * 64 + cA0 * 8);
    fa[1] = *(const float4*)(xA + 0 * 64 + cA0 * 8 + 4);
    fa[2] = *(const float4*)(xA + 0 * 64 + cA1 * 8);
    fa[3] = *(const float4*)(xA + 0 * 64 + cA1 * 8 + 4);
#pragma unroll
    for (int i = 0; i < 4; ++i)
      ub[i] = *(const uint4v*)(WB + 0 * 64 + (cB0 + i) * 8);

#pragma unroll
    for (int kt = 0; kt < 4; ++kt) {
      char* Ab = lds + (kt & 1) * 8192;
      char* Bb = lds + 16384 + (kt & 1) * 16384;
      // DSW (vmcnt wait auto-inserted at first use of fa/ub)
      *(half8*)(Ab + aw0) = cvt8(fa[0], fa[1]);
      *(half8*)(Ab + aw1) = cvt8(fa[2], fa[3]);
#pragma unroll
      for (int i = 0; i < 4; ++i) *(uint4v*)(Bb + bw[i]) = ub[i];
      // early-issue next K-step loads (hide HBM/L3 latency under compute)
      if (kt < 3) {
        fa[0] = *(const float4*)(xA + (kt + 1) * 64 + cA0 * 8);
        fa[1] = *(const float4*)(xA + (kt + 1) * 64 + cA0 * 8 + 4);
        fa[2] = *(const float4*)(xA + (kt + 1) * 64 + cA1 * 8);
        fa[3] = *(const float4*)(xA + (kt + 1) * 64 + cA1 * 8 + 4);
#pragma unroll
        for (int i = 0; i < 4; ++i)
          ub[i] = *(const uint4v*)(WB + (kt + 1) * 64 + (cB0 + i) * 8);
      }
      __syncthreads();
      // COMPUTE buf kt&1: 2 ks x (2 A-frags + 4 B-frags ds_read, 8 MFMA)
      {
        const char* Ar = Ab; const char* Br = Bb;
#pragma unroll
        for (int ks = 0; ks < 2; ++ks) {
          unsigned ko = ks ? koff1 : koff0;
          half8 xf0 = *(const half8*)(Ar + raw0 + ko);
          half8 xf1 = *(const half8*)(Ar + raw1 + ko);
          half8 wf0 = *(const half8*)(Br + rbw[0] + ko);
          half8 wf1 = *(const half8*)(Br + rbw[1] + ko);
          half8 wf2 = *(const half8*)(Br + rbw[2] + ko);
          half8 wf3 = *(const half8*)(Br + rbw[3] + ko);
          acc[0][0] = __builtin_amdgcn_mfma_f32_16x16x32_f16(wf0, xf0, acc[0][0], 0, 0, 0);
          acc[0][1] = __builtin_amdgcn_mfma_f32_16x16x32_f16(wf1, xf0, acc[0][1], 0, 0, 0);
          acc[0][2] = __builtin_amdgcn_mfma_f32_16x16x32_f16(wf2, xf0, acc[0][2], 0, 0, 0);
          acc[0][3] = __builtin_amdgcn_mfma_f32_16x16x32_f16(wf3, xf0, acc[0][3], 0, 0, 0);
          acc[1][0] = __builtin_amdgcn_mfma_f32_16x16x32_f16(wf0, xf1, acc[1][0], 0, 0, 0);
          acc[1][1] = __builtin_amdgcn_mfma_f32_16x16x32_f16(wf1, xf1, acc[1][1], 0, 0, 0);
          acc[1][2] = __builtin_amdgcn_mfma_f32_16x16x32_f16(wf2, xf1, acc[1][2], 0, 0, 0);
          acc[1][3] = __builtin_amdgcn_mfma_f32_16x16x32_f16(wf3, xf1, acc[1][3], 0, 0, 0);
        }
      }
    }

    // epilogue: wave writes 32 nodes x 64 contiguous cols
#pragma unroll
    for (int mi = 0; mi < 2; ++mi) {
      int nd = nodebase + mi * 16;
      if (nd < n) {
        size_t ob = (size_t)nd * HID + wn * 64 + lhi * 4;
        float s1 = ss[mi];
#pragma unroll
        for (int ni = 0; ni < 4; ++ni) {
          half4v o;
          o[0] = (_Float16)(acc[mi][ni][0] * s1); o[1] = (_Float16)(acc[mi][ni][1] * s1);
          o[2] = (_Float16)(acc[mi][ni][2] * s1); o[3] = (_Float16)(acc[mi][ni][3] * s1);
          *(half4v*)(dst + ob + ni * 16) = o;
        }
        if (w == 2) {
          float s2 = sk[mi];
#pragma unroll
          for (int ni = 0; ni < 4; ++ni) {
            half4v o2;
            o2[0] = (_Float16)(acc[mi][ni][0] * s2); o2[1] = (_Float16)(acc[mi][ni][1] * s2);
            o2[2] = (_Float16)(acc[mi][ni][2] * s2); o2[3] = (_Float16)(acc[mi][ni][3] * s2);
            *(half4v*)(gF2k + ob + ni * 16) = o2;
          }
        }
      }
    }
  }
}

// ---------------- SpMM (fp16 features, 16B/lane gathers) ----------------
// One wave per dest node. g = lane>>4 (edge slot), c = lane&15 (16B chunk).
// mode 0: *1/deg -> fp16; mode 1: *rsqrt(deg) -> fp32; mode 2: mode1 + addsrc.

__device__ inline float2 h2f2(unsigned int u) {
  __half2 h; *(unsigned int*)&h = u; return __half22float2(h);
}

__global__ __launch_bounds__(256) void k_spmm_h(
    const _Float16* __restrict__ gin, void* __restrict__ gout,
    const int* __restrict__ csr, const int* __restrict__ offs, const int* __restrict__ cnt,
    int n, int mode, const float* __restrict__ addsrc)
{
  int w = (blockIdx.x << 2) | ((int)threadIdx.x >> 6);
  if (w >= n) return;
  int lane = threadIdx.x & 63;
  int g = lane >> 4;
  int c = lane & 15;
  int beg = offs[w], end = offs[w + 1];

  float acc[8];
#pragma unroll
  for (int i = 0; i < 8; ++i) acc[i] = 0.f;

  int e = beg;
#pragma unroll 1
  for (; e + 16 <= end; e += 16) {
    int idx[4];
#pragma unroll
    for (int j = 0; j < 4; ++j) idx[j] = csr[e + 4 * j + g];
    uint4v u[4];
#pragma unroll
    for (int j = 0; j < 4; ++j)
      u[j] = *(const uint4v*)(gin + ((size_t)(unsigned)idx[j] << 7) + c * 8);
#pragma unroll
    for (int j = 0; j < 4; ++j)
#pragma unroll
      for (int q = 0; q < 4; ++q) {
        float2 v = h2f2(u[j][q]);
        acc[q * 2] += v.x; acc[q * 2 + 1] += v.y;
      }
  }
#pragma unroll 1
  for (; e + 4 <= end; e += 4) {
    int idx = csr[e + g];
    uint4v u = *(const uint4v*)(gin + ((size_t)(unsigned)idx << 7) + c * 8);
#pragma unroll
    for (int q = 0; q < 4; ++q) {
      float2 v = h2f2(u[q]);
      acc[q * 2] += v.x; acc[q * 2 + 1] += v.y;
    }
  }
  {
    int rem = end - e;
    if (g < rem) {
      int idx = csr[e + g];
      uint4v u = *(const uint4v*)(gin + ((size_t)(unsigned)idx << 7) + c * 8);
#pragma unroll
      for (int q = 0; q < 4; ++q) {
        float2 v = h2f2(u[q]);
        acc[q * 2] += v.x; acc[q * 2 + 1] += v.y;
      }
    }
  }
  // reduce across the 4 g-groups
#pragma unroll
  for (int i = 0; i < 8; ++i) {
    acc[i] += __shfl_xor(acc[i], 16, 64);
    acc[i] += __shfl_xor(acc[i], 32, 64);
  }
  // self loop
  {
    uint4v u = *(const uint4v*)(gin + ((size_t)w << 7) + c * 8);
#pragma unroll
    for (int q = 0; q < 4; ++q) {
      float2 v = h2f2(u[q]);
      acc[q * 2] += v.x; acc[q * 2 + 1] += v.y;
    }
  }

  float deg = (float)(cnt[w] + 1);
  if (mode == 0) {
    float sc = 1.0f / deg;
    if (g == 0) {
      uint4v o;
#pragma unroll
      for (int q = 0; q < 4; ++q) {
        __half2 h = __float22half2_rn(make_float2(acc[q * 2] * sc, acc[q * 2 + 1] * sc));
        o[q] = *(unsigned int*)&h;
      }
      *(uint4v*)((_Float16*)gout + ((size_t)w << 7) + c * 8) = o;
    }
  } else {
    float sc = rsqrtf(deg);
    if (g == 0) {
      float o[8];
#pragma unroll
      for (int i = 0; i < 8; ++i) o[i] = acc[i] * sc;
      if (mode == 2) {
        const float* ap = addsrc + ((size_t)w << 7) + c * 8;
        float4 a0 = *(const float4*)ap;
        float4 a1 = *(const float4*)(ap + 4);
        o[0] += a0.x; o[1] += a0.y; o[2] += a0.z; o[3] += a0.w;
        o[4] += a1.x; o[5] += a1.y; o[6] += a1.z; o[7] += a1.w;
      }
      float* op = (float*)gout + ((size_t)w << 7) + c * 8;
      *(float4*)op = make_float4(o[0], o[1], o[2], o[3]);
      *(float4*)(op + 4) = make_float4(o[4], o[5], o[6], o[7]);
    }
  }
}

// 3 feature matrices propagated in one pass over the graph (shared steps 1,2)
__global__ __launch_bounds__(256) void k_spmm3(
    const _Float16* __restrict__ g0, const _Float16* __restrict__ g1,
    const _Float16* __restrict__ g2,
    void* __restrict__ o0, void* __restrict__ o1, void* __restrict__ o2,
    int md0, int md1, int md2,
    const int* __restrict__ csr, const int* __restrict__ offs, const int* __restrict__ cnt,
    int n)
{
  int w = (blockIdx.x << 2) | ((int)threadIdx.x >> 6);
  if (w >= n) return;
  int lane = threadIdx.x & 63;
  int g = lane >> 4;
  int c = lane & 15;
  int beg = offs[w], end = offs[w + 1];

  float a0[8], a1[8], a2[8];
#pragma unroll
  for (int i = 0; i < 8; ++i) { a0[i] = 0.f; a1[i] = 0.f; a2[i] = 0.f; }

  int e = beg;
#pragma unroll 1
  for (; e + 4 <= end; e += 4) {
    size_t off = ((size_t)(unsigned)csr[e + g] << 7) + c * 8;
    uint4v u0 = *(const uint4v*)(g0 + off);
    uint4v u1 = *(const uint4v*)(g1 + off);
    uint4v u2 = *(const uint4v*)(g2 + off);
#pragma unroll
    for (int q = 0; q < 4; ++q) {
      float2 v;
      v = h2f2(u0[q]); a0[q * 2] += v.x; a0[q * 2 + 1] += v.y;
      v = h2f2(u1[q]); a1[q * 2] += v.x; a1[q * 2 + 1] += v.y;
      v = h2f2(u2[q]); a2[q * 2] += v.x; a2[q * 2 + 1] += v.y;
    }
  }
  {
    int rem = end - e;
    if (g < rem) {
      size_t off = ((size_t)(unsigned)csr[e + g] << 7) + c * 8;
      uint4v u0 = *(const uint4v*)(g0 + off);
      uint4v u1 = *(const uint4v*)(g1 + off);
      uint4v u2 = *(const uint4v*)(g2 + off);
#pragma unroll
      for (int q = 0; q < 4; ++q) {
        float2 v;
        v = h2f2(u0[q]); a0[q * 2] += v.x; a0[q * 2 + 1] += v.y;
        v = h2f2(u1[q]); a1[q * 2] += v.x; a1[q * 2 + 1] += v.y;
        v = h2f2(u2[q]); a2[q * 2] += v.x; a2[q * 2 + 1] += v.y;
      }
    }
  }
#pragma unroll
  for (int i = 0; i < 8; ++i) {
    a0[i] += __shfl_xor(a0[i], 16, 64); a0[i] += __shfl_xor(a0[i], 32, 64);
    a1[i] += __shfl_xor(a1[i], 16, 64); a1[i] += __shfl_xor(a1[i], 32, 64);
    a2[i] += __shfl_xor(a2[i], 16, 64); a2[i] += __shfl_xor(a2[i], 32, 64);
  }
  // self loops
  {
    size_t off = ((size_t)w << 7) + c * 8;
    uint4v u0 = *(const uint4v*)(g0 + off);
    uint4v u1 = *(const uint4v*)(g1 + off);
    uint4v u2 = *(const uint4v*)(g2 + off);
#pragma unroll
    for (int q = 0; q < 4; ++q) {
      float2 v;
      v = h2f2(u0[q]); a0[q * 2] += v.x; a0[q * 2 + 1] += v.y;
      v = h2f2(u1[q]); a1[q * 2] += v.x; a1[q * 2 + 1] += v.y;
      v = h2f2(u2[q]); a2[q * 2] += v.x; a2[q * 2 + 1] += v.y;
    }
  }

  float deg = (float)(cnt[w] + 1);
  if (g == 0) {
    float inv = 1.0f / deg, rs = rsqrtf(deg);
    {
      float sc = (md0 == 0) ? inv : rs;
      if (md0 == 0) {
        uint4v o;
#pragma unroll
        for (int q = 0; q < 4; ++q) {
          __half2 h = __float22half2_rn(make_float2(a0[q * 2] * sc, a0[q * 2 + 1] * sc));
          o[q] = *(unsigned int*)&h;
        }
        *(uint4v*)((_Float16*)o0 + ((size_t)w << 7) + c * 8) = o;
      } else {
        float* op = (float*)o0 + ((size_t)w << 7) + c * 8;
        *(float4*)op = make_float4(a0[0] * sc, a0[1] * sc, a0[2] * sc, a0[3] * sc);
        *(float4*)(op + 4) = make_float4(a0[4] * sc, a0[5] * sc, a0[6] * sc, a0[7] * sc);
      }
    }
    {
      float sc = (md1 == 0) ? inv : rs;
      if (md1 == 0) {
        uint4v o;
#pragma unroll
        for (int q = 0; q < 4; ++q) {
          __half2 h = __float22half2_rn(make_float2(a1[q * 2] * sc, a1[q * 2 + 1] * sc));
          o[q] = *(unsigned int*)&h;
        }
        *(uint4v*)((_Float16*)o1 + ((size_t)w << 7) + c * 8) = o;
      } else {
        float* op = (float*)o1 + ((size_t)w << 7) + c * 8;
        *(float4*)op = make_float4(a1[0] * sc, a1[1] * sc, a1[2] * sc, a1[3] * sc);
        *(float4*)(op + 4) = make_float4(a1[4] * sc, a1[5] * sc, a1[6] * sc, a1[7] * sc);
      }
    }
    {
      float sc = (md2 == 0) ? inv : rs;
      if (md2 == 0) {
        uint4v o;
#pragma unroll
        for (int q = 0; q < 4; ++q) {
          __half2 h = __float22half2_rn(make_float2(a2[q * 2] * sc, a2[q * 2 + 1] * sc));
          o[q] = *(unsigned int*)&h;
        }
        *(uint4v*)((_Float16*)o2 + ((size_t)w << 7) + c * 8) = o;
      } else {
        float* op = (float*)o2 + ((size_t)w << 7) + c * 8;
        *(float4*)op = make_float4(a2[0] * sc, a2[1] * sc, a2[2] * sc, a2[3] * sc);
        *(float4*)(op + 4) = make_float4(a2[4] * sc, a2[5] * sc, a2[6] * sc, a2[7] * sc);
      }
    }
  }
}

// ---------------- launch ----------------

extern "C" void kernel_launch(void* const* d_in, const int* in_sizes, int n_in,
                              void* d_out, int out_size, void* d_ws, size_t ws_size,
                              hipStream_t stream) {
  const float* x    = (const float*)d_in[0];
  const int*   ei   = (const int*)d_in[1];
  const int*   knn  = (const int*)d_in[2];
  const float* W_s1 = (const float*)d_in[3];
  const float* b_s1 = (const float*)d_in[4];
  const float* W_s2 = (const float*)d_in[5];
  const float* b_s2 = (const float*)d_in[6];
  const float* W_f2 = (const float*)d_in[7];
  const float* b_f2 = (const float*)d_in[8];

  const int N  = in_sizes[0] / F_IN;
  const int E  = in_sizes[1] / 2;
  const int EK = in_sizes[2] / 2;
  const int* row_s = ei;   const int* col_s = ei + E;
  const int* row_k = knn;  const int* col_k = knn + EK;

  char* p = (char*)d_ws;
  auto carve = [&](size_t bytes) {
    char* r = p; p += (bytes + 511) & ~(size_t)511; return (void*)r;
  };
  int* cnt_s = (int*)carve((size_t)N * 4);
  int* cnt_k = (int*)carve((size_t)N * 4);
  int* cur_s = (int*)carve((size_t)N * 4);
  int* cur_k = (int*)carve((size_t)N * 4);
  char* zero_end = p;
  int* offs_s = (int*)carve((size_t)(N + 1) * 4);
  int* offs_k = (int*)carve((size_t)(N + 1) * 4);
  int* bsum   = (int*)carve(4096);
  int* csr_s  = (int*)carve((size_t)E * 4);
  int* csr_k  = (int*)carve((size_t)EK * 4);
  _Float16* Wh  = (_Float16*)carve((size_t)3 * HID * F_IN * 2);
  _Float16* gS1 = (_Float16*)carve((size_t)N * HID * 2);
  _Float16* gS2 = (_Float16*)carve((size_t)N * HID * 2);
  _Float16* gF2s= (_Float16*)carve((size_t)N * HID * 2);
  _Float16* gF2k= (_Float16*)carve((size_t)N * HID * 2);
  _Float16* tS2 = (_Float16*)carve((size_t)N * HID * 2);

  float* out_h0 = (float*)d_out;
  float* out_h1 = out_h0 + (size_t)N * HID;
  float* out_z0 = out_h1 + (size_t)N * HID;
  float* out_z1 = out_z0 + (size_t)N * HID;
  // z1 region (fp32, N*HID floats = 2x fp16 buffers) is free until the very last
  // launch -> scratch for the two single-use step-1 outputs.
  _Float16* tS1 = (_Float16*)out_z1;
  _Float16* tF2 = tS1 + (size_t)N * HID;

  hipMemsetAsync(d_ws, 0, (size_t)(zero_end - (char*)d_ws), stream);

  const int tpb = 256;
  int etot = E + EK;
  k_count2<<<(etot + tpb - 1) / tpb, tpb, 0, stream>>>(col_s, E, cnt_s, col_k, EK, cnt_k);

  int nb = (N + 1023) / 1024;
  k_scan_block<<<nb, 1024, 0, stream>>>(cnt_s, N, offs_s, bsum);
  k_scan_single<<<1, 64, 0, stream>>>(bsum, nb, offs_s + N);
  k_add_off<<<(N + tpb - 1) / tpb, tpb, 0, stream>>>(offs_s, bsum, N);
  k_scan_block<<<nb, 1024, 0, stream>>>(cnt_k, N, offs_k, bsum);
  k_scan_single<<<1, 64, 0, stream>>>(bsum, nb, offs_k + N);
  k_add_off<<<(N + tpb - 1) / tpb, tpb, 0, stream>>>(offs_k, bsum, N);

  k_scatter2<<<(etot + tpb - 1) / tpb, tpb, 0, stream>>>(
      row_s, col_s, E, offs_s, cur_s, csr_s,
      row_k, col_k, EK, offs_k, cur_k, csr_k);

  k_cvt_w<<<96, 256, 0, stream>>>(W_s1, W_s2, W_f2, Wh);
  k_gemm3<<<(N + 63) / 64, 256, 0, stream>>>(x, Wh, b_s1, b_s2, b_f2, N, cnt_s, cnt_k,
                                             gS1, gS2, gF2s, gF2k);

  int spmm_grid = (N + 3) / 4;

  // step 1 (all chains), step 2 (s1 & f2 finalize, s2 continues)
  k_spmm3<<<spmm_grid, 256, 0, stream>>>(gS1, gS2, gF2s,
                                         tS1, tS2, tF2, 0, 0, 0,
                                         csr_s, offs_s, cnt_s, N);
  k_spmm3<<<spmm_grid, 256, 0, stream>>>(tS1, tS2, tF2,
                                         out_h0, gS1, out_z0, 1, 0, 1,
                                         csr_s, offs_s, cnt_s, N);

  // s2 steps 3..10: ping-pong gS1 <-> tS2
  {
    _Float16* cur = gS1; _Float16* alt = tS2;
    for (int it = 0; it < 7; ++it) {
      k_spmm_h<<<spmm_grid, 256, 0, stream>>>(cur, alt,
                                              csr_s, offs_s, cnt_s, N, 0, nullptr);
      _Float16* t = cur; cur = alt; alt = t;
    }
    k_spmm_h<<<spmm_grid, 256, 0, stream>>>(cur, out_h1,
                                            csr_s, offs_s, cnt_s, N, 1, nullptr);
  }

  // knn step (last: frees the z1 scratch region before writing it)
  k_spmm_h<<<spmm_grid, 256, 0, stream>>>(gF2k, out_z1,
                                          csr_k, offs_k, cnt_k, N, 2,
                                          out_z0);
}